// Round 1
// 123.539 us; speedup vs baseline: 1.0227x; 1.0227x over previous
//
#include <hip/hip_runtime.h>
#include <stdint.h>

// ScoreNet: S[b] = (x_b Wq^T)(x_b Wk^T)^T * (1/sqrt(R)) + diag(x_b Wd^T + bd), * max(ls, 0.01)
// B=16, L=2048 -> N=1024, C=256, H*R=192.
//
// R7: fuse fold+proj. k_pack (48 blk) transposes W fp32 -> bf16 chunk layout
// Wt[kc][row][8] so B-fragments load straight from global (L2-resident,
// 256 B coalesced per 16-lane group). k_fproj (256 blk x 512 thr) folds its
// 64 rows once into swizzled LDS (computing dvec in the same pass), then runs
// the full K=256 MFMA loop after a SINGLE barrier -- no per-kk barriers, no
// xb intermediate (8 MB write + 6x L2 re-read eliminated). k_score unchanged.

#define HD_SCALE 0.17677669529663687f  // 1/sqrt(32)

typedef __bf16 bf16_t;
typedef bf16_t bf16x8 __attribute__((ext_vector_type(8)));
typedef float f32x4 __attribute__((ext_vector_type(4)));
typedef unsigned short ushort8_t __attribute__((ext_vector_type(8)));

__device__ __forceinline__ unsigned short f2bf(float f) {
  unsigned int u = __float_as_uint(f);
  return (unsigned short)((u + 0x7fffu + ((u >> 16) & 1u)) >> 16);
}

__device__ __forceinline__ void gload16(const void* g, void* l) {
  __builtin_amdgcn_global_load_lds(
      (const __attribute__((address_space(1))) void*)g,
      (__attribute__((address_space(3))) void*)l, 16, 0, 0);
}

// ---------------------------------------------------------------------------
// Kernel 1: pack W = [Wq;Wk] fp32 -> bf16 in fragment-chunk-transposed layout:
//   Wt[(kc*384 + row)*8 + e] = W[row][kc*8 + e],  kc in [0,32), row in [0,384).
// A 16-lane group loading fragment (kc, row..row+15) reads 256 B contiguous.
// ---------------------------------------------------------------------------
__global__ __launch_bounds__(256) void k_pack(const float* __restrict__ Wq,
                                              const float* __restrict__ Wk,
                                              unsigned short* __restrict__ Wt) {
  const int flat = blockIdx.x * 256 + threadIdx.x;  // 0..12287
  const int kc = flat / 384;
  const int row = flat - kc * 384;
  const float* src =
      (row < 192) ? (Wq + (size_t)row * 256) : (Wk + (size_t)(row - 192) * 256);
  const float4 a = *(const float4*)(src + kc * 8);
  const float4 b = *(const float4*)(src + kc * 8 + 4);
  ushort8_t v;
  v[0] = f2bf(a.x); v[1] = f2bf(a.y); v[2] = f2bf(a.z); v[3] = f2bf(a.w);
  v[4] = f2bf(b.x); v[5] = f2bf(b.y); v[6] = f2bf(b.z); v[7] = f2bf(b.w);
  *(ushort8_t*)(Wt + (size_t)flat * 8) = v;
}

// ---------------------------------------------------------------------------
// Kernel 2 (fused): fold 64 feats row-pairs -> bf16 LDS tile (XOR-swizzled),
// dvec = x.Wd + bd from the fp32 folds, then QK[64][384] = x @ W^T via MFMA.
// 256 blocks x 512 threads (8 waves: 2 row-groups x 4 col-groups of 96).
// One __syncthreads() total; B-frags stream from L2-resident Wt.
// ---------------------------------------------------------------------------
__global__ __launch_bounds__(512) void k_fproj(const float* __restrict__ feats,
                                               const float* __restrict__ Wd,
                                               const float* __restrict__ bd,
                                               const unsigned short* __restrict__ Wt,
                                               float* __restrict__ dvec,
                                               unsigned short* __restrict__ QK) {
  __shared__ unsigned short As[64 * 256];  // 32 KB bf16, swizzled 16B chunks
  const int t = threadIdx.x;
  const int m0 = blockIdx.x * 64;

  // ---- fold + d: thread t owns row t>>3, chunks kc = (t&7) + 8q ----
  {
    const int row = t >> 3;  // 0..63
    const int gr = m0 + row;
    const int b = gr >> 10, n = gr & 1023;
    const float* r0 = feats + ((size_t)b * 2049 + 1 + 2 * n) * 256;
    float dot = 0.f;
#pragma unroll
    for (int q = 0; q < 4; ++q) {
      const int kc = (t & 7) + q * 8;  // 0..31; per-instr lanes cover all 8 kc%8
      const float4 p0a = *(const float4*)(r0 + kc * 8);
      const float4 p0b = *(const float4*)(r0 + kc * 8 + 4);
      const float4 p1a = *(const float4*)(r0 + 256 + kc * 8);
      const float4 p1b = *(const float4*)(r0 + 256 + kc * 8 + 4);
      const float4 wa = *(const float4*)(Wd + kc * 8);
      const float4 wb = *(const float4*)(Wd + kc * 8 + 4);
      const float x0 = (p0a.x + p1a.x) * 0.5f, x1 = (p0a.y + p1a.y) * 0.5f;
      const float x2 = (p0a.z + p1a.z) * 0.5f, x3 = (p0a.w + p1a.w) * 0.5f;
      const float x4 = (p0b.x + p1b.x) * 0.5f, x5 = (p0b.y + p1b.y) * 0.5f;
      const float x6 = (p0b.z + p1b.z) * 0.5f, x7 = (p0b.w + p1b.w) * 0.5f;
      dot += x0 * wa.x + x1 * wa.y + x2 * wa.z + x3 * wa.w +
             x4 * wb.x + x5 * wb.y + x6 * wb.z + x7 * wb.w;
      ushort8_t v;
      v[0] = f2bf(x0); v[1] = f2bf(x1); v[2] = f2bf(x2); v[3] = f2bf(x3);
      v[4] = f2bf(x4); v[5] = f2bf(x5); v[6] = f2bf(x6); v[7] = f2bf(x7);
      const int pos = kc ^ (row & 7);  // bank-spread: 2-way max per 16 lanes
      *(ushort8_t*)&As[(row * 32 + pos) * 8] = v;
    }
    // 8 lanes per row (t&7 = 0..7, same wave): tree-reduce the dot
    dot += __shfl_down(dot, 4, 64);
    dot += __shfl_down(dot, 2, 64);
    dot += __shfl_down(dot, 1, 64);
    if ((t & 7) == 0) dvec[gr] = dot + bd[0];
  }
  __syncthreads();  // the only barrier

  // ---- GEMM: wave (wr,wc) owns rows wr*32..+31, cols wc*96..+95 ----
  const int w = t >> 6, l = t & 63;
  const int wr = w >> 2, wc = w & 3;
  const int quad = l >> 4, lr = l & 15;

  f32x4 acc[2][6] = {};
#pragma unroll
  for (int kk = 0; kk < 4; ++kk) {
#pragma unroll
    for (int s = 0; s < 2; ++s) {
      const int kc = kk * 8 + s * 4 + quad;  // 0..31
      bf16x8 a[2], bb[6];
#pragma unroll
      for (int i = 0; i < 2; ++i) {
        const int row = wr * 32 + i * 16 + lr;
        const int pos = kc ^ (row & 7);
        a[i] = *(const bf16x8*)&As[(row * 32 + pos) * 8];
      }
#pragma unroll
      for (int j = 0; j < 6; ++j) {
        const int row = wc * 96 + j * 16 + lr;
        bb[j] = *(const bf16x8*)(Wt + ((size_t)kc * 384 + row) * 8);
      }
#pragma unroll
      for (int i = 0; i < 2; ++i)
#pragma unroll
        for (int j = 0; j < 6; ++j)
          acc[i][j] = __builtin_amdgcn_mfma_f32_16x16x32_bf16(a[i], bb[j],
                                                              acc[i][j], 0, 0, 0);
    }
  }

#pragma unroll
  for (int i = 0; i < 2; ++i)
#pragma unroll
    for (int j = 0; j < 6; ++j)
#pragma unroll
      for (int r = 0; r < 4; ++r) {
        const int rowq = m0 + wr * 32 + i * 16 + quad * 4 + r;
        const int col = wc * 96 + j * 16 + lr;
        QK[(size_t)rowq * 384 + col] = f2bf(acc[i][j][r]);
      }
}

// ---------------------------------------------------------------------------
// Kernel 3: S[b] = Q[b] @ K[b]^T * HD_SCALE (+ diag d) * ls  (unchanged R6)
// 128x128 tile, BK=64 (3 iters), XOR-swizzled LDS, XCD-aware batch remap.
// ---------------------------------------------------------------------------
__global__ __launch_bounds__(256) void k_score(const unsigned short* __restrict__ QK,
                                               const float* __restrict__ dvec,
                                               const float* __restrict__ logit_scale,
                                               float* __restrict__ out) {
  __shared__ unsigned short As[128 * 64];  // 16 KB
  __shared__ unsigned short Bs[128 * 64];  // 16 KB
  const int t = threadIdx.x;
  const int w = t >> 6, l = t & 63;

  // flat 0..1023 over grid (8,8,16), x-fastest dispatch order
  const int flat = blockIdx.x + (blockIdx.y << 3) + (blockIdx.z << 6);
  const int xcd = flat & 7, j0 = flat >> 3;            // j0 in [0,128)
  const int b = (xcd << 1) | (j0 >> 6);                // batch 0..15
  const int jj = j0 & 63;
  const int mt = jj & 7, nt = jj >> 3;

  const int m0 = mt * 128;  // cols of S (K rows)
  const int n0 = nt * 128;  // rows of S (Q rows)
  const int wm = w >> 1, wn = w & 1;
  const int quad = l >> 4, lr = l & 15;
  const size_t qbase = (size_t)b * 1024 * 384;

  f32x4 acc[4][4] = {};

  for (int kk = 0; kk < 3; ++kk) {
    const int k0 = kk * 64;
    __syncthreads();
#pragma unroll
    for (int i = 0; i < 4; ++i) {
      const int e = i * 256 + t;
      const int row = e >> 3;
      const int kc = (e & 7) ^ (row & 7);
      gload16(QK + qbase + (size_t)(n0 + row) * 384 + k0 + kc * 8,
              &As[(i * 256 + (w << 6)) * 8]);
      gload16(QK + qbase + (size_t)(m0 + row) * 384 + 192 + k0 + kc * 8,
              &Bs[(i * 256 + (w << 6)) * 8]);
    }
    __syncthreads();

#pragma unroll
    for (int s = 0; s < 2; ++s) {
      bf16x8 a[4], bb[4];
#pragma unroll
      for (int i = 0; i < 4; ++i) {
        const int row = wm * 64 + i * 16 + lr;
        const int pos = (s * 4 + quad) ^ (row & 7);
        a[i] = *(const bf16x8*)&As[row * 64 + pos * 8];
      }
#pragma unroll
      for (int j = 0; j < 4; ++j) {
        const int row = wn * 64 + j * 16 + lr;
        const int pos = (s * 4 + quad) ^ (row & 7);
        bb[j] = *(const bf16x8*)&Bs[row * 64 + pos * 8];
      }
#pragma unroll
      for (int i = 0; i < 4; ++i)
#pragma unroll
        for (int j = 0; j < 4; ++j)
          acc[i][j] = __builtin_amdgcn_mfma_f32_16x16x32_bf16(a[i], bb[j],
                                                              acc[i][j], 0, 0, 0);
    }
  }

  const float ls = fmaxf(logit_scale[0], 0.01f);
  const bool diag_block = (m0 == n0);
#pragma unroll
  for (int i = 0; i < 4; ++i)
#pragma unroll
    for (int j = 0; j < 4; ++j)
#pragma unroll
      for (int r = 0; r < 4; ++r) {
        const int nr = n0 + wm * 64 + i * 16 + quad * 4 + r;  // S row
        const int mc = m0 + wn * 64 + j * 16 + lr;            // S col
        float v = acc[i][j][r] * HD_SCALE;
        if (diag_block && nr == mc) v += dvec[b * 1024 + nr];
        __builtin_nontemporal_store(v * ls,
            &out[((size_t)b << 20) + (size_t)nr * 1024 + mc]);
      }
}

// ---------------------------------------------------------------------------
extern "C" void kernel_launch(void* const* d_in, const int* in_sizes, int n_in,
                              void* d_out, int out_size, void* d_ws, size_t ws_size,
                              hipStream_t stream) {
  const float* feats = (const float*)d_in[0];  // (16, 2049, 256)
  const float* Wq = (const float*)d_in[1];     // (192, 256)
  const float* Wk = (const float*)d_in[2];     // (192, 256)
  const float* Wd = (const float*)d_in[3];     // (1, 256)
  const float* bd = (const float*)d_in[4];     // (1,)
  const float* ls = (const float*)d_in[5];     // scalar
  float* out = (float*)d_out;                  // (16, 1024, 1024) fp32

  uint8_t* ws = (uint8_t*)d_ws;
  unsigned short* QK = (unsigned short*)ws;                             // 12 MB bf16 [Q|K]
  float* dvec = (float*)(ws + (12u << 20));                             // 64 KB fp32 d
  unsigned short* Wt = (unsigned short*)(ws + (12u << 20) + (64u << 10));  // 192 KB bf16 W^T-chunks

  hipLaunchKernelGGL(k_pack, dim3(48), dim3(256), 0, stream, Wq, Wk, Wt);
  hipLaunchKernelGGL(k_fproj, dim3(256), dim3(512), 0, stream, feats, Wd, bd, Wt,
                     dvec, QK);
  hipLaunchKernelGGL(k_score, dim3(8, 8, 16), dim3(256), 0, stream, QK, dvec, ls, out);
}